// Round 4
// baseline (366.494 us; speedup 1.0000x reference)
//
#include <hip/hip_runtime.h>
#include <math.h>

#define NB 4
#define NPT 4096
#define KNN 20
#define C1 64
#define C2 128
#define C3 256
#define BN_EPS 1e-5f
#define NCH 8
#define CHSZ 512   // NPT / NCH
#define BATCH 32
#define BSTRIDE 36 // u8 buffer row stride: 9 dwords, coprime with 32 banks
#define TCAP 32

// pd must be computed bit-identically in k1_part and k1_collect: pin contraction off.
__device__ __forceinline__ float pd_of(float4 q, float nxx, float4 c) {
#pragma clang fp contract(off)
  float dot = fmaf(q.z, c.z, fmaf(q.y, c.y, q.x * c.x));
  float inner = -2.0f * dot;
  return (nxx - inner) - c.w;
}

// ---------------- K0: pack {x,y,z,xx} ----------------
__global__ __launch_bounds__(256) void k0_pack(const float* __restrict__ x, float4* __restrict__ xp) {
  int i = blockIdx.x * 256 + threadIdx.x;
  if (i >= NB * NPT) return;
  float a = x[i*3+0], b = x[i*3+1], c = x[i*3+2];
  float xx = fmaf(c, c, fmaf(b, b, a*a));
  xp[i] = make_float4(a, b, c, xx);
}

// ---------------- K1a: per-chunk top-20 VALUES (f32 multiset, filter+drain) ----------------
__global__ __launch_bounds__(256) void k1_part(const float4* __restrict__ xp,
                                               float* __restrict__ part) {
  __shared__ float4 pts[CHSZ];                       // 8 KiB
  __shared__ unsigned char buf[256 * BSTRIDE];       // 9 KiB
  int blk = blockIdx.x;                 // 512 blocks = 64 qgroups x 8 chunks
  int ch = blk & (NCH - 1);
  int qg = blk >> 3;
  int b = qg >> 4;
  int qbase = (qg & 15) << 8;
  const float4* xb = xp + b * NPT;
  int cbase = ch * CHSZ;
  for (int t = threadIdx.x; t < CHSZ; t += 256) pts[t] = xb[cbase + t];
  __syncthreads();

  int n = qbase + threadIdx.x;
  float4 q = xb[n];
  float nxx = -q.w;
  float keys[KNN];
#pragma unroll
  for (int t = 0; t < KNN; ++t) keys[t] = -INFINITY;
  unsigned char* mybuf = buf + threadIdx.x * BSTRIDE;

#pragma unroll 1
  for (int bs = 0; bs < CHSZ; bs += BATCH) {
    int cnt = 0;
    float thr = keys[KNN-1];
    // branchless filter: unconditional byte store, conditional count bump
#pragma unroll
    for (int jj = 0; jj < BATCH; ++jj) {
      float pd = pd_of(q, nxx, pts[bs + jj]);        // wave-uniform LDS broadcast
      mybuf[cnt] = (unsigned char)jj;
      cnt += (pd >= thr) ? 1 : 0;                    // >= admits equal values (multiset)
    }
    // drain: wave iterates max-over-lanes(cnt), lanes predicated; bubble is pure f32
#pragma unroll 1
    for (int cc = 0; __any(cc < cnt); ++cc) {
      if (cc < cnt) {
        int j = bs + mybuf[cc];
        float pd = pd_of(q, nxx, pts[j]);
        if (pd > keys[KNN-1]) {                      // strict > : exact multiset top-20
          float cv = pd;
#pragma unroll
          for (int t = 0; t < KNN; ++t) {
            float hi = fmaxf(cv, keys[t]);
            cv = fminf(cv, keys[t]);
            keys[t] = hi;
          }
        }
      }
    }
  }
  float* out = part + ((size_t)(b * NPT + n) * NCH + ch) * KNN;
#pragma unroll
  for (int t = 0; t < KNN; ++t) out[t] = keys[t];    // sorted desc
}

// ---------------- K1b: merge 8 sorted 20-lists -> exact 20th-largest value ----------------
__global__ __launch_bounds__(256) void k1_thr(const float* __restrict__ part,
                                              float* __restrict__ thr) {
  int qq = blockIdx.x * 256 + threadIdx.x;           // 64 blocks
  const float* pp = part + (size_t)qq * (NCH * KNN);
  float keys[KNN];
  {
    const float4* c4 = (const float4*)pp;
    float4 a0 = c4[0], a1 = c4[1], a2 = c4[2], a3 = c4[3], a4 = c4[4];
    keys[0]=a0.x; keys[1]=a0.y; keys[2]=a0.z; keys[3]=a0.w;
    keys[4]=a1.x; keys[5]=a1.y; keys[6]=a1.z; keys[7]=a1.w;
    keys[8]=a2.x; keys[9]=a2.y; keys[10]=a2.z; keys[11]=a2.w;
    keys[12]=a3.x; keys[13]=a3.y; keys[14]=a3.z; keys[15]=a3.w;
    keys[16]=a4.x; keys[17]=a4.y; keys[18]=a4.z; keys[19]=a4.w;
  }
#pragma unroll 1
  for (int ch = 1; ch < NCH; ++ch) {
    const float4* c4 = (const float4*)(pp + ch * KNN);
    float4 a0 = c4[0], a1 = c4[1], a2 = c4[2], a3 = c4[3], a4 = c4[4];
    float vs[KNN];
    vs[0]=a0.x; vs[1]=a0.y; vs[2]=a0.z; vs[3]=a0.w;
    vs[4]=a1.x; vs[5]=a1.y; vs[6]=a1.z; vs[7]=a1.w;
    vs[8]=a2.x; vs[9]=a2.y; vs[10]=a2.z; vs[11]=a2.w;
    vs[12]=a3.x; vs[13]=a3.y; vs[14]=a3.z; vs[15]=a3.w;
    vs[16]=a4.x; vs[17]=a4.y; vs[18]=a4.z; vs[19]=a4.w;
#pragma unroll
    for (int t = 0; t < KNN; ++t) {                  // fully unrolled: static vs[] indexing
      float v = vs[t];
      if (v <= keys[KNN-1]) break;                   // list sorted desc: rest can't insert
      float cv = v;
#pragma unroll
      for (int s = 0; s < KNN; ++s) {
        float hi = fmaxf(cv, keys[s]);
        cv = fminf(cv, keys[s]);
        keys[s] = hi;
      }
    }
  }
  thr[qq] = keys[KNN-1];
}

// ---------------- K1c: collect indices with pd > thr (and ties == thr) ----------------
__global__ __launch_bounds__(256) void k1_collect(const float4* __restrict__ xp,
    const float* __restrict__ thr, int* __restrict__ nbr, int* __restrict__ gcnt,
    int* __restrict__ tlist, int* __restrict__ tcnt) {
  __shared__ float4 pts[CHSZ];
  int blk = blockIdx.x;                 // 512 blocks = 64 qgroups x 8 chunks
  int ch = blk & (NCH - 1);
  int qg = blk >> 3;
  int b = qg >> 4;
  int qbase = (qg & 15) << 8;
  const float4* xb = xp + b * NPT;
  int cbase = ch * CHSZ;
  for (int t = threadIdx.x; t < CHSZ; t += 256) pts[t] = xb[cbase + t];
  __syncthreads();

  int n = qbase + threadIdx.x;
  int q = b * NPT + n;
  float4 qq = xb[n];
  float nxx = -qq.w;
  float T = thr[q];
#pragma unroll 4
  for (int j = 0; j < CHSZ; ++j) {
    float pd = pd_of(qq, nxx, pts[j]);
    if (pd >= T) {
      int idx = cbase + j;
      if (pd > T) {                                  // guaranteed <= 19 of these globally
        int p = atomicAdd(gcnt + q, 1);
        nbr[(size_t)q * KNN + p] = idx;
      } else {                                       // tie at threshold
        int p = atomicAdd(tcnt + q, 1);
        if (p < TCAP) tlist[(size_t)q * TCAP + p] = idx;
      }
    }
  }
}

// ---------------- K1d: fill remaining slots with smallest-index ties ----------------
__global__ __launch_bounds__(256) void k1_fill(const int* __restrict__ gcnt,
    const int* __restrict__ tcnt, const int* __restrict__ tlist, int* __restrict__ nbr) {
  int q = blockIdx.x * 256 + threadIdx.x;            // 64 blocks
  int gc = gcnt[q];
  int tc = min(tcnt[q], TCAP);
  int need = KNN - gc;
  unsigned used = 0;
#pragma unroll 1
  for (int s = 0; s < need; ++s) {
    int best = 0x7fffffff, bi = -1;
#pragma unroll 1
    for (int t2 = 0; t2 < tc; ++t2) {
      if (!((used >> t2) & 1)) {
        int v2 = tlist[(size_t)q * TCAP + t2];
        if (v2 < best) { best = v2; bi = t2; }
      }
    }
    if (bi >= 0) { used |= 1u << bi; nbr[(size_t)q * KNN + gc + s] = best; }
  }
}

// ---------------- K2: edge-conv 6->64 + BN + ReLU + max over K (out-split x4) ----------------
__global__ __launch_bounds__(256) void k2_edge(const float4* __restrict__ xp, const int* __restrict__ nbr,
    const float* __restrict__ w1, const float* __restrict__ g1, const float* __restrict__ b1,
    const float* __restrict__ m1, const float* __restrict__ v1, float* __restrict__ h1) {
  __shared__ float4 sa[C1], se[C1];
  int tid = threadIdx.x;
  if (tid < C1) {
    int o = tid;
    float inv = g1[o] / sqrtf(v1[o] + BN_EPS);
    float bb = b1[o] - m1[o] * inv;
    const float* w = w1 + o * 6;
    sa[o] = make_float4(w[0]*inv, w[1]*inv, w[2]*inv, 0.f);
    se[o] = make_float4((w[3]-w[0])*inv, (w[4]-w[1])*inv, (w[5]-w[2])*inv, bb);
  }
  __syncthreads();
  int gp = blockIdx.x * 64 + (tid & 63);    // 256 blocks, 4 threads per query
  int quad = tid >> 6;
  int b = gp >> 12, n = gp & (NPT - 1);
  const float4* xb = xp + b * NPT;
  float4 q = xb[n];
  float4 nb[KNN];
  const int* nr = nbr + (size_t)gp * KNN;
#pragma unroll
  for (int k = 0; k < KNN; ++k) nb[k] = xb[nr[k]];
  float* out = h1 + (size_t)gp * C1;
  int obase = quad * 16;
#pragma unroll 1
  for (int o = obase; o < obase + 16; o += 4) {
    float4 res;
    float* rp = &res.x;
#pragma unroll
    for (int oo = 0; oo < 4; ++oo) {
      float4 a = sa[o+oo], e = se[o+oo];
      float mx = -INFINITY;
#pragma unroll
      for (int k = 0; k < KNN; ++k)
        mx = fmaxf(mx, fmaf(a.z, nb[k].z, fmaf(a.y, nb[k].y, a.x * nb[k].x)));
      float base = fmaf(e.z, q.z, fmaf(e.y, q.y, e.x * q.x)) + e.w;
      rp[oo] = fmaxf(mx + base, 0.f);
    }
    *(float4*)(out + o) = res;
  }
}

// ---------------- K3: conv 64->128 + BN + ReLU (out-quarter split) ----------------
__global__ __launch_bounds__(256) void k3_conv2(const float* __restrict__ h1,
    const float* __restrict__ w2, const float* __restrict__ g2, const float* __restrict__ b2,
    const float* __restrict__ m2, const float* __restrict__ v2, float* __restrict__ h2) {
  __shared__ float4 sw[32 * 16];
  __shared__ float sb[32];
  int qd = blockIdx.x & 3, ng = blockIdx.x >> 2;   // 256 blocks
  int obase = qd * 32;
  if (threadIdx.x < 32) {
    int o = obase + threadIdx.x;
    float inv = g2[o] / sqrtf(v2[o] + BN_EPS);
    sb[threadIdx.x] = b2[o] - m2[o] * inv;
  }
  for (int t = threadIdx.x; t < 32 * 16; t += 256) {
    int o = obase + (t >> 4);
    float inv = g2[o] / sqrtf(v2[o] + BN_EPS);
    float4 w = ((const float4*)w2)[o * 16 + (t & 15)];
    sw[t] = make_float4(w.x*inv, w.y*inv, w.z*inv, w.w*inv);
  }
  __syncthreads();
  int gp = ng * 256 + threadIdx.x;
  float4 r[16];
  const float4* row = (const float4*)(h1 + (size_t)gp * C1);
#pragma unroll
  for (int i = 0; i < 16; ++i) r[i] = row[i];
  float* out = h2 + (size_t)gp * C2 + obase;
#pragma unroll 1
  for (int o = 0; o < 32; o += 4) {
    float4 res;
    float* rp = &res.x;
#pragma unroll
    for (int oo = 0; oo < 4; ++oo) {
      const float4* wrow = &sw[(o+oo) * 16];
      float acc = 0.f;
#pragma unroll
      for (int i = 0; i < 16; ++i) {
        float4 w = wrow[i];
        acc = fmaf(r[i].x, w.x, acc);
        acc = fmaf(r[i].y, w.y, acc);
        acc = fmaf(r[i].z, w.z, acc);
        acc = fmaf(r[i].w, w.w, acc);
      }
      rp[oo] = fmaxf(acc + sb[o+oo], 0.f);
    }
    *(float4*)(out + o) = res;
  }
}

// ---------------- K4: conv 128->256 + BN + ReLU fused with global max (out-split x8) ----------------
__global__ __launch_bounds__(256) void k4_conv3max(const float* __restrict__ h2,
    const float* __restrict__ w3, const float* __restrict__ g3, const float* __restrict__ b3,
    const float* __restrict__ m3, const float* __restrict__ v3, float* __restrict__ feat) {
  __shared__ float4 sw[32 * 32];            // 16 KiB: 32 outs x 128 in
  __shared__ float sb[32], sinv[32];
  __shared__ float lw[4 * 32];
  int bid = blockIdx.x;                     // 512 = b4 x nt16 x oq8
  int oq = bid & 7, nt = (bid >> 3) & 15, b = bid >> 7;
  int obase = oq * 32;
  if (threadIdx.x < 32) {
    int o = obase + threadIdx.x;
    float inv = g3[o] / sqrtf(v3[o] + BN_EPS);
    sinv[threadIdx.x] = inv;
    sb[threadIdx.x] = b3[o] - m3[o] * inv;
  }
  __syncthreads();
  for (int t = threadIdx.x; t < 32 * 32; t += 256) {
    float4 w = ((const float4*)w3)[(obase + (t >> 5)) * 32 + (t & 31)];
    float inv = sinv[t >> 5];
    sw[t] = make_float4(w.x*inv, w.y*inv, w.z*inv, w.w*inv);
  }
  __syncthreads();
  int n = nt * 256 + threadIdx.x;
  float4 r[32];
  const float4* row = (const float4*)(h2 + (size_t)(b * NPT + n) * C2);
#pragma unroll
  for (int i = 0; i < 32; ++i) r[i] = row[i];
  int lane = threadIdx.x & 63, wid = threadIdx.x >> 6;
#pragma unroll 1
  for (int ol = 0; ol < 32; ++ol) {
    const float4* wrow = &sw[ol * 32];
    float acc = 0.f;
#pragma unroll
    for (int i = 0; i < 32; ++i) {
      float4 w = wrow[i];
      acc = fmaf(r[i].x, w.x, acc);
      acc = fmaf(r[i].y, w.y, acc);
      acc = fmaf(r[i].z, w.z, acc);
      acc = fmaf(r[i].w, w.w, acc);
    }
    float v = fmaxf(acc + sb[ol], 0.f);
#pragma unroll
    for (int m = 32; m; m >>= 1) v = fmaxf(v, __shfl_xor(v, m));
    if (lane == 0) lw[wid * 32 + ol] = v;
  }
  __syncthreads();
  if (threadIdx.x < 32) {
    float m0 = fmaxf(fmaxf(lw[threadIdx.x], lw[32 + threadIdx.x]),
                     fmaxf(lw[64 + threadIdx.x], lw[96 + threadIdx.x]));
    atomicMax((int*)feat + b * C3 + obase + threadIdx.x, __float_as_int(m0));
  }
}

// ---------------- K6: FC head ----------------
__global__ __launch_bounds__(256) void k6_fc(const float* __restrict__ feat,
    const float* __restrict__ fc1w, const float* __restrict__ fc1b,
    const float* __restrict__ fc2w, const float* __restrict__ fc2b, float* __restrict__ out) {
  __shared__ float sf[NB * C3];
  __shared__ float sh[NB * 128];
  for (int t = threadIdx.x; t < NB * C3; t += 256) sf[t] = feat[t];
  __syncthreads();
  for (int t = threadIdx.x; t < NB * 128; t += 256) {
    int b = t >> 7, o = t & 127;
    float acc = fc1b[o];
    const float* w = fc1w + o * C3;
    const float* f = sf + b * C3;
    for (int c = 0; c < C3; ++c) acc = fmaf(f[c], w[c], acc);
    sh[t] = fmaxf(acc, 0.f);
  }
  __syncthreads();
  for (int t = threadIdx.x; t < NB * 40; t += 256) {
    int b = t / 40, o = t % 40;
    float acc = fc2b[o];
    const float* w = fc2w + o * 128;
    const float* hh = sh + b * 128;
    for (int c = 0; c < 128; ++c) acc = fmaf(hh[c], w[c], acc);
    out[b * 40 + o] = acc;
  }
}

extern "C" void kernel_launch(void* const* d_in, const int* in_sizes, int n_in,
                              void* d_out, int out_size, void* d_ws, size_t ws_size,
                              hipStream_t stream) {
  (void)in_sizes; (void)n_in; (void)out_size; (void)ws_size;
  const float* x   = (const float*)d_in[0];
  const float* w1  = (const float*)d_in[1];
  const float* g1  = (const float*)d_in[2];
  const float* b1  = (const float*)d_in[3];
  const float* m1  = (const float*)d_in[4];
  const float* v1  = (const float*)d_in[5];
  const float* w2  = (const float*)d_in[6];
  const float* g2  = (const float*)d_in[7];
  const float* b2  = (const float*)d_in[8];
  const float* m2  = (const float*)d_in[9];
  const float* v2  = (const float*)d_in[10];
  const float* w3  = (const float*)d_in[11];
  const float* g3  = (const float*)d_in[12];
  const float* b3  = (const float*)d_in[13];
  const float* m3  = (const float*)d_in[14];
  const float* v3  = (const float*)d_in[15];
  const float* f1w = (const float*)d_in[16];
  const float* f1b = (const float*)d_in[17];
  const float* f2w = (const float*)d_in[18];
  const float* f2b = (const float*)d_in[19];

  char* ws = (char*)d_ws;
  // layout (peak ~14 MB):
  float4* xp    = (float4*)ws;                      // [0, 256K)
  float*  feat  = (float*)(ws + 0x40000);           // [256K, +4K)
  float*  thr   = (float*)(ws + 0x48000);           // [288K, +64K)
  int*    gcnt  = (int*)  (ws + 0x58000);           // [352K, +64K)
  int*    tcnt  = (int*)  (ws + 0x68000);           // [416K, +64K)
  int*    nbr   = (int*)  (ws + 0x80000);           // [512K, +1.25M)
  float*  part  = (float*)(ws + 0x200000);          // [2M, 12M)     dead after k1_thr
  int*    tlist = (int*)  (ws + 0xC00000);          // [12M, 14M)    dead after k1_fill
  float*  h1    = (float*)(ws + 0x200000);          // [2M, 6M)      overlays part
  float*  h2    = (float*)(ws + 0x600000);          // [6M, 14M)     overlays part+tlist

  hipMemsetAsync(feat, 0, NB * C3 * sizeof(float), stream);
  hipMemsetAsync(gcnt, 0, 2 * NB * NPT * sizeof(int), stream);  // gcnt+tcnt contiguous
  k0_pack    <<<64, 256, 0, stream>>>(x, xp);
  k1_part    <<<512, 256, 0, stream>>>(xp, part);
  k1_thr     <<<64, 256, 0, stream>>>(part, thr);
  k1_collect <<<512, 256, 0, stream>>>(xp, thr, nbr, gcnt, tlist, tcnt);
  k1_fill    <<<64, 256, 0, stream>>>(gcnt, tcnt, tlist, nbr);
  k2_edge    <<<256, 256, 0, stream>>>(xp, nbr, w1, g1, b1, m1, v1, h1);
  k3_conv2   <<<256, 256, 0, stream>>>(h1, w2, g2, b2, m2, v2, h2);
  k4_conv3max<<<512, 256, 0, stream>>>(h2, w3, g3, b3, m3, v3, feat);
  k6_fc      <<<1, 256, 0, stream>>>(feat, f1w, f1b, f2w, f2b, (float*)d_out);
}

// Round 5
// 211.180 us; speedup vs baseline: 1.7355x; 1.7355x over previous
//
#include <hip/hip_runtime.h>
#include <math.h>

#define NB 4
#define NPT 4096
#define KNN 20
#define C1 64
#define C2 128
#define C3 256
#define BN_EPS 1e-5f

// pd must be computed identically in both scan phases: pin contraction off.
__device__ __forceinline__ float pd_xyz(float4 q, float nxx, float cx, float cy, float cz) {
#pragma clang fp contract(off)
  float cw = fmaf(cz, cz, fmaf(cy, cy, cx * cx));        // == k0's xx chain
  float dot = fmaf(q.z, cz, fmaf(q.y, cy, q.x * cx));
  float inner = -2.0f * dot;
  return (nxx - inner) - cw;
}

// ---------------- K0: pack {x,y,z,xx} ----------------
__global__ __launch_bounds__(256) void k0_pack(const float* __restrict__ x, float4* __restrict__ xp) {
  int i = blockIdx.x * 256 + threadIdx.x;
  if (i >= NB * NPT) return;
  float a = x[i*3+0], b = x[i*3+1], c = x[i*3+2];
  float xx = fmaf(c, c, fmaf(b, b, a*a));
  xp[i] = make_float4(a, b, c, xx);
}

// ---------------- K1: fused exact kNN, warp-per-query, distributed top-20 ----------------
// 8 queries per 512-thread block; candidates staged once (SoA, 48KB).
// Phase A: exact 20th-largest value via distributed sorted list (lane t = t-th largest).
// Phase B: rescan, compact-write indices pd>T, ties pd==T in index order (lax.top_k stable).
__global__ __launch_bounds__(512) void k1_knn(const float4* __restrict__ xp, int* __restrict__ nbr) {
  __shared__ float2 sxy[NPT];          // 32 KB
  __shared__ float  sz[NPT];           // 16 KB
  __shared__ int    tl[8][32];         // 1 KB tie lists
  int bb = (blockIdx.x * 8) >> 12;     // batch (blocks never straddle batches: 512/batch)
  const float4* xb = xp + bb * NPT;
  for (int t = threadIdx.x; t < NPT; t += 512) {
    float4 c = xb[t];
    sxy[t] = make_float2(c.x, c.y);
    sz[t] = c.z;
  }
  __syncthreads();

  int lane = threadIdx.x & 63;
  int wq = threadIdx.x >> 6;                    // query slot in block (0..7)
  int q = blockIdx.x * 8 + wq;                  // global query 0..16383
  int n = q & (NPT - 1);
  float4 qv = xb[n];
  float nxx = -qv.w;

  // ---- Phase A: threshold (exact 20th largest pd value) ----
  float key = -INFINITY;                        // lane t holds t-th largest (t<20 meaningful)
  float thr = -INFINITY;                        // == key at lane 19
#pragma unroll 2
  for (int s = 0; s < NPT / 64; ++s) {
    int j = s * 64 + lane;
    float2 cxy = sxy[j];
    float cz = sz[j];
    float pd = pd_xyz(qv, nxx, cxy.x, cxy.y, cz);
    unsigned long long m = __ballot(pd > thr);
    while (m) {
      int src = __ffsll((unsigned long long)m) - 1;
      m &= m - 1;
      float v = __shfl(pd, src);
      if (v > thr) {                            // uniform: skip stale survivors
        float kup = __shfl_up(key, 1);
        if (lane == 0) kup = INFINITY;
        key = (key > v) ? key : ((kup > v) ? v : kup);
        thr = __shfl(key, 19);
      }
    }
  }
  float T = thr;

  // ---- Phase B: collect indices. count(pd>T) <= 19 always; ties complete to 20. ----
  int gc = 0, tc = 0;
  int* nq = nbr + (size_t)q * KNN;
  unsigned long long mylt = (lane == 0) ? 0ull : (~0ull >> (64 - lane));
#pragma unroll 2
  for (int s = 0; s < NPT / 64; ++s) {
    int j = s * 64 + lane;
    float2 cxy = sxy[j];
    float cz = sz[j];
    float pd = pd_xyz(qv, nxx, cxy.x, cxy.y, cz);
    unsigned long long mg = __ballot(pd > T);
    unsigned long long mt = __ballot(pd == T);
    if (pd > T) {
      int r = __popcll(mg & mylt);
      nq[gc + r] = j;
    }
    gc += __popcll(mg);
    if (mt) {
      if (pd == T) {
        int slot = tc + __popcll(mt & mylt);
        if (slot < 32) tl[wq][slot] = j;        // need<=20<32: first-20 ties always kept
      }
      tc += __popcll(mt);
    }
  }
  int need = KNN - gc;                          // >= 1
  if (lane < need) nq[gc + lane] = tl[wq][lane];
}

// ---------------- K2: edge-conv 6->64 + BN + ReLU + max over K (out-split x8) ----------------
__global__ __launch_bounds__(256) void k2_edge(const float4* __restrict__ xp, const int* __restrict__ nbr,
    const float* __restrict__ w1, const float* __restrict__ g1, const float* __restrict__ b1,
    const float* __restrict__ m1, const float* __restrict__ v1, float* __restrict__ h1) {
  __shared__ float4 sa[C1], se[C1];
  int tid = threadIdx.x;
  if (tid < C1) {
    int o = tid;
    float inv = g1[o] / sqrtf(v1[o] + BN_EPS);
    float bb = b1[o] - m1[o] * inv;
    const float* w = w1 + o * 6;
    sa[o] = make_float4(w[0]*inv, w[1]*inv, w[2]*inv, 0.f);
    se[o] = make_float4((w[3]-w[0])*inv, (w[4]-w[1])*inv, (w[5]-w[2])*inv, bb);
  }
  __syncthreads();
  int gp = blockIdx.x * 32 + (tid & 31);    // 512 blocks, 8 threads per query
  int oct = tid >> 5;                       // out octant (8 outs each)
  int b = gp >> 12, n = gp & (NPT - 1);
  const float4* xb = xp + b * NPT;
  float4 q = xb[n];
  float4 nb[KNN];
  const int* nr = nbr + (size_t)gp * KNN;
#pragma unroll
  for (int k = 0; k < KNN; ++k) nb[k] = xb[nr[k]];
  float* out = h1 + (size_t)gp * C1;
  int obase = oct * 8;
#pragma unroll 1
  for (int o = obase; o < obase + 8; o += 4) {
    float4 res;
    float* rp = &res.x;
#pragma unroll
    for (int oo = 0; oo < 4; ++oo) {
      float4 a = sa[o+oo], e = se[o+oo];
      float mx = -INFINITY;
#pragma unroll
      for (int k = 0; k < KNN; ++k)
        mx = fmaxf(mx, fmaf(a.z, nb[k].z, fmaf(a.y, nb[k].y, a.x * nb[k].x)));
      float base = fmaf(e.z, q.z, fmaf(e.y, q.y, e.x * q.x)) + e.w;
      rp[oo] = fmaxf(mx + base, 0.f);
    }
    *(float4*)(out + o) = res;
  }
}

// ---------------- K3: conv 64->128 + BN + ReLU (out-split x8) ----------------
__global__ __launch_bounds__(256) void k3_conv2(const float* __restrict__ h1,
    const float* __restrict__ w2, const float* __restrict__ g2, const float* __restrict__ b2,
    const float* __restrict__ m2, const float* __restrict__ v2, float* __restrict__ h2) {
  __shared__ float4 sw[16 * 16];            // 4 KiB: this block's 16 outs
  __shared__ float sb[16];
  int qd = blockIdx.x & 7, ng = blockIdx.x >> 3;   // 512 blocks
  int obase = qd * 16;
  if (threadIdx.x < 16) {
    int o = obase + threadIdx.x;
    float inv = g2[o] / sqrtf(v2[o] + BN_EPS);
    sb[threadIdx.x] = b2[o] - m2[o] * inv;
  }
  for (int t = threadIdx.x; t < 16 * 16; t += 256) {
    int o = obase + (t >> 4);
    float inv = g2[o] / sqrtf(v2[o] + BN_EPS);
    float4 w = ((const float4*)w2)[o * 16 + (t & 15)];
    sw[t] = make_float4(w.x*inv, w.y*inv, w.z*inv, w.w*inv);
  }
  __syncthreads();
  int gp = ng * 256 + threadIdx.x;
  float4 r[16];
  const float4* row = (const float4*)(h1 + (size_t)gp * C1);
#pragma unroll
  for (int i = 0; i < 16; ++i) r[i] = row[i];
  float* out = h2 + (size_t)gp * C2 + obase;
#pragma unroll 1
  for (int o = 0; o < 16; o += 4) {
    float4 res;
    float* rp = &res.x;
#pragma unroll
    for (int oo = 0; oo < 4; ++oo) {
      const float4* wrow = &sw[(o+oo) * 16];
      float acc = 0.f;
#pragma unroll
      for (int i = 0; i < 16; ++i) {
        float4 w = wrow[i];
        acc = fmaf(r[i].x, w.x, acc);
        acc = fmaf(r[i].y, w.y, acc);
        acc = fmaf(r[i].z, w.z, acc);
        acc = fmaf(r[i].w, w.w, acc);
      }
      rp[oo] = fmaxf(acc + sb[o+oo], 0.f);
    }
    *(float4*)(out + o) = res;
  }
}

// ---------------- K4: conv 128->256 + BN + ReLU fused with global max (out-split x8) ----------------
__global__ __launch_bounds__(256) void k4_conv3max(const float* __restrict__ h2,
    const float* __restrict__ w3, const float* __restrict__ g3, const float* __restrict__ b3,
    const float* __restrict__ m3, const float* __restrict__ v3, float* __restrict__ feat) {
  __shared__ float4 sw[32 * 32];            // 16 KiB: 32 outs x 128 in
  __shared__ float sb[32], sinv[32];
  __shared__ float lw[4 * 32];
  int bid = blockIdx.x;                     // 512 = b4 x nt16 x oq8
  int oq = bid & 7, nt = (bid >> 3) & 15, b = bid >> 7;
  int obase = oq * 32;
  if (threadIdx.x < 32) {
    int o = obase + threadIdx.x;
    float inv = g3[o] / sqrtf(v3[o] + BN_EPS);
    sinv[threadIdx.x] = inv;
    sb[threadIdx.x] = b3[o] - m3[o] * inv;
  }
  __syncthreads();
  for (int t = threadIdx.x; t < 32 * 32; t += 256) {
    float4 w = ((const float4*)w3)[(obase + (t >> 5)) * 32 + (t & 31)];
    float inv = sinv[t >> 5];
    sw[t] = make_float4(w.x*inv, w.y*inv, w.z*inv, w.w*inv);
  }
  __syncthreads();
  int n = nt * 256 + threadIdx.x;
  float4 r[32];
  const float4* row = (const float4*)(h2 + (size_t)(b * NPT + n) * C2);
#pragma unroll
  for (int i = 0; i < 32; ++i) r[i] = row[i];
  int lane = threadIdx.x & 63, wid = threadIdx.x >> 6;
#pragma unroll 1
  for (int ol = 0; ol < 32; ++ol) {
    const float4* wrow = &sw[ol * 32];
    float acc = 0.f;
#pragma unroll
    for (int i = 0; i < 32; ++i) {
      float4 w = wrow[i];
      acc = fmaf(r[i].x, w.x, acc);
      acc = fmaf(r[i].y, w.y, acc);
      acc = fmaf(r[i].z, w.z, acc);
      acc = fmaf(r[i].w, w.w, acc);
    }
    float v = fmaxf(acc + sb[ol], 0.f);
#pragma unroll
    for (int m = 32; m; m >>= 1) v = fmaxf(v, __shfl_xor(v, m));
    if (lane == 0) lw[wid * 32 + ol] = v;
  }
  __syncthreads();
  if (threadIdx.x < 32) {
    float m0 = fmaxf(fmaxf(lw[threadIdx.x], lw[32 + threadIdx.x]),
                     fmaxf(lw[64 + threadIdx.x], lw[96 + threadIdx.x]));
    atomicMax((int*)feat + b * C3 + obase + threadIdx.x, __float_as_int(m0));
  }
}

// ---------------- K6: FC head ----------------
__global__ __launch_bounds__(256) void k6_fc(const float* __restrict__ feat,
    const float* __restrict__ fc1w, const float* __restrict__ fc1b,
    const float* __restrict__ fc2w, const float* __restrict__ fc2b, float* __restrict__ out) {
  __shared__ float sf[NB * C3];
  __shared__ float sh[NB * 128];
  for (int t = threadIdx.x; t < NB * C3; t += 256) sf[t] = feat[t];
  __syncthreads();
  for (int t = threadIdx.x; t < NB * 128; t += 256) {
    int b = t >> 7, o = t & 127;
    float acc = fc1b[o];
    const float* w = fc1w + o * C3;
    const float* f = sf + b * C3;
    for (int c = 0; c < C3; ++c) acc = fmaf(f[c], w[c], acc);
    sh[t] = fmaxf(acc, 0.f);
  }
  __syncthreads();
  for (int t = threadIdx.x; t < NB * 40; t += 256) {
    int b = t / 40, o = t % 40;
    float acc = fc2b[o];
    const float* w = fc2w + o * 128;
    const float* hh = sh + b * 128;
    for (int c = 0; c < 128; ++c) acc = fmaf(hh[c], w[c], acc);
    out[b * 40 + o] = acc;
  }
}

extern "C" void kernel_launch(void* const* d_in, const int* in_sizes, int n_in,
                              void* d_out, int out_size, void* d_ws, size_t ws_size,
                              hipStream_t stream) {
  (void)in_sizes; (void)n_in; (void)out_size; (void)ws_size;
  const float* x   = (const float*)d_in[0];
  const float* w1  = (const float*)d_in[1];
  const float* g1  = (const float*)d_in[2];
  const float* b1  = (const float*)d_in[3];
  const float* m1  = (const float*)d_in[4];
  const float* v1  = (const float*)d_in[5];
  const float* w2  = (const float*)d_in[6];
  const float* g2  = (const float*)d_in[7];
  const float* b2  = (const float*)d_in[8];
  const float* m2  = (const float*)d_in[9];
  const float* v2  = (const float*)d_in[10];
  const float* w3  = (const float*)d_in[11];
  const float* g3  = (const float*)d_in[12];
  const float* b3  = (const float*)d_in[13];
  const float* m3  = (const float*)d_in[14];
  const float* v3  = (const float*)d_in[15];
  const float* f1w = (const float*)d_in[16];
  const float* f1b = (const float*)d_in[17];
  const float* f2w = (const float*)d_in[18];
  const float* f2b = (const float*)d_in[19];

  char* ws = (char*)d_ws;
  float4* xp   = (float4*)ws;                  // [0, 256K)
  float*  feat = (float*)(ws + 0x40000);       // [256K, +4K)
  int*    nbr  = (int*)  (ws + 0x80000);       // [512K, +1.25M)
  float*  h1   = (float*)(ws + 0x200000);      // [2M, 6M)
  float*  h2   = (float*)(ws + 0x600000);      // [6M, 14M)

  hipMemsetAsync(feat, 0, NB * C3 * sizeof(float), stream);
  k0_pack    <<<64, 256, 0, stream>>>(x, xp);
  k1_knn     <<<2048, 512, 0, stream>>>(xp, nbr);
  k2_edge    <<<512, 256, 0, stream>>>(xp, nbr, w1, g1, b1, m1, v1, h1);
  k3_conv2   <<<512, 256, 0, stream>>>(h1, w2, g2, b2, m2, v2, h2);
  k4_conv3max<<<512, 256, 0, stream>>>(h2, w3, g3, b3, m3, v3, feat);
  k6_fc      <<<1, 256, 0, stream>>>(feat, f1w, f1b, f2w, f2b, (float*)d_out);
}

// Round 6
// 154.139 us; speedup vs baseline: 2.3777x; 1.3701x over previous
//
#include <hip/hip_runtime.h>
#include <math.h>

#define NB 4
#define NPT 4096
#define KNN 20
#define C1 64
#define C2 128
#define C3 256
#define BN_EPS 1e-5f

// pd must be computed identically everywhere: pin contraction off.
// c.w = |c|^2 precomputed by k0 with the same fma chain as the reference xx.
__device__ __forceinline__ float pd_of(float4 q, float nxx, float4 c) {
#pragma clang fp contract(off)
  float dot = fmaf(q.z, c.z, fmaf(q.y, c.y, q.x * c.x));
  float inner = -2.0f * dot;
  return (nxx - inner) - c.w;
}

// ---------------- K0: pack {x,y,z,xx} ----------------
__global__ __launch_bounds__(256) void k0_pack(const float* __restrict__ x, float4* __restrict__ xp) {
  int i = blockIdx.x * 256 + threadIdx.x;
  if (i >= NB * NPT) return;
  float a = x[i*3+0], b = x[i*3+1], c = x[i*3+2];
  float xx = fmaf(c, c, fmaf(b, b, a*a));
  xp[i] = make_float4(a, b, c, xx);
}

// ---------------- K1: fused exact kNN, wave-per-query, seeded distributed top-20 ----------------
// 16 queries per 1024-thread block, full candidate set staged as float4 (64 KB, 2 blocks/CU).
// Prepass: lane-max + wave bitonic sort -> m = 20th-largest lane-max (provably <= T20).
// Scan: u64 keys (value-desc, index-asc tiebreak = lax.top_k order), distributed sorted
// top-20 across lanes 0..19; insert events gated by (pd >= m) && (key > k19)  ~> ~25/query.
__global__ __launch_bounds__(1024) void k1_knn(const float4* __restrict__ xp, int* __restrict__ nbr) {
  __shared__ float4 pts[NPT];               // 64 KB exactly
  int bb = blockIdx.x >> 8;                 // 256 blocks per batch (never straddles)
  const float4* xb = xp + bb * NPT;
  for (int t = threadIdx.x; t < NPT; t += 1024) pts[t] = xb[t];
  __syncthreads();

  int lane = threadIdx.x & 63;
  int wq = threadIdx.x >> 6;                // 0..15
  int q = blockIdx.x * 16 + wq;
  int n = q & (NPT - 1);
  float4 qv = pts[n];
  float nxx = -qv.w;

  // ---- prepass: per-lane max over 64 strided candidates (no events, pure throughput) ----
  float lmax = -INFINITY;
#pragma unroll 4
  for (int s = 0; s < NPT / 64; ++s) {
    float pd = pd_of(qv, nxx, pts[s * 64 + lane]);
    lmax = fmaxf(lmax, pd);
  }
  // wave bitonic sort (ascending); m = element 44 = 20th largest lane-max
  float v = lmax;
#pragma unroll
  for (int k = 2; k <= 64; k <<= 1) {
#pragma unroll
    for (int j2 = k >> 1; j2 > 0; j2 >>= 1) {
      float o = __shfl_xor(v, j2);
      bool keepmin = (((lane & k) == 0) == ((lane & j2) == 0));
      float mn = fminf(v, o), mx = fmaxf(v, o);
      v = keepmin ? mn : mx;
    }
  }
  float m = __shfl(v, 64 - KNN);            // m <= true 20th-largest pd (exact bound)

  // ---- single scan with index-carrying keys ----
  unsigned long long lst = 0ull;            // lane t holds t-th largest key (t<20 meaningful)
  unsigned long long k19 = 0ull;            // current 20th-largest key (wave-uniform)
  int rl = 4095 - lane;
#pragma unroll 2
  for (int s = 0; s < NPT / 64; ++s) {
    float pd = pd_of(qv, nxx, pts[s * 64 + lane]);
    int ib = __float_as_int(pd);
    unsigned uk = (unsigned)(ib ^ ((ib >> 31) | 0x80000000));   // monotone f32->u32, never 0
    unsigned long long cand = ((unsigned long long)uk << 12) | (unsigned)(rl - s * 64);
    unsigned long long mm = __ballot(pd >= m && cand > k19);
    while (mm) {
      int src = __ffsll(mm) - 1;
      mm &= mm - 1;
      unsigned long long cv = __shfl(cand, src);
      if (cv > k19) {                       // wave-uniform; skips stale survivors
        unsigned long long kup = __shfl_up(lst, 1);
        if (lane == 0) kup = ~0ull;
        lst = (lst > cv) ? lst : ((kup > cv) ? cv : kup);
        k19 = __shfl(lst, 19);
      }
    }
  }
  // lanes 0..19 hold top-20 keys desc (ties: ascending index) = lax.top_k order
  if (lane < KNN) nbr[(size_t)q * KNN + lane] = 4095 - (int)(lst & 0xFFF);
}

// ---------------- K2: edge-conv 6->64 + BN + ReLU + max over K (out-split x8) ----------------
__global__ __launch_bounds__(256) void k2_edge(const float4* __restrict__ xp, const int* __restrict__ nbr,
    const float* __restrict__ w1, const float* __restrict__ g1, const float* __restrict__ b1,
    const float* __restrict__ m1, const float* __restrict__ v1, float* __restrict__ h1) {
  __shared__ float4 sa[C1], se[C1];
  int tid = threadIdx.x;
  if (tid < C1) {
    int o = tid;
    float inv = g1[o] / sqrtf(v1[o] + BN_EPS);
    float bb = b1[o] - m1[o] * inv;
    const float* w = w1 + o * 6;
    sa[o] = make_float4(w[0]*inv, w[1]*inv, w[2]*inv, 0.f);
    se[o] = make_float4((w[3]-w[0])*inv, (w[4]-w[1])*inv, (w[5]-w[2])*inv, bb);
  }
  __syncthreads();
  int gp = blockIdx.x * 32 + (tid & 31);    // 512 blocks, 8 threads per query
  int oct = tid >> 5;                       // out octant (8 outs each)
  int b = gp >> 12, n = gp & (NPT - 1);
  const float4* xb = xp + b * NPT;
  float4 q = xb[n];
  float4 nb[KNN];
  const int* nr = nbr + (size_t)gp * KNN;
#pragma unroll
  for (int k = 0; k < KNN; ++k) nb[k] = xb[nr[k]];
  float* out = h1 + (size_t)gp * C1;
  int obase = oct * 8;
#pragma unroll 1
  for (int o = obase; o < obase + 8; o += 4) {
    float4 res;
    float* rp = &res.x;
#pragma unroll
    for (int oo = 0; oo < 4; ++oo) {
      float4 a = sa[o+oo], e = se[o+oo];
      float mx = -INFINITY;
#pragma unroll
      for (int k = 0; k < KNN; ++k)
        mx = fmaxf(mx, fmaf(a.z, nb[k].z, fmaf(a.y, nb[k].y, a.x * nb[k].x)));
      float base = fmaf(e.z, q.z, fmaf(e.y, q.y, e.x * q.x)) + e.w;
      rp[oo] = fmaxf(mx + base, 0.f);
    }
    *(float4*)(out + o) = res;
  }
}

// ---------------- K3: conv 64->128 + BN + ReLU (out-split x8) ----------------
__global__ __launch_bounds__(256) void k3_conv2(const float* __restrict__ h1,
    const float* __restrict__ w2, const float* __restrict__ g2, const float* __restrict__ b2,
    const float* __restrict__ m2, const float* __restrict__ v2, float* __restrict__ h2) {
  __shared__ float4 sw[16 * 16];            // 4 KiB: this block's 16 outs
  __shared__ float sb[16];
  int qd = blockIdx.x & 7, ng = blockIdx.x >> 3;   // 512 blocks
  int obase = qd * 16;
  if (threadIdx.x < 16) {
    int o = obase + threadIdx.x;
    float inv = g2[o] / sqrtf(v2[o] + BN_EPS);
    sb[threadIdx.x] = b2[o] - m2[o] * inv;
  }
  for (int t = threadIdx.x; t < 16 * 16; t += 256) {
    int o = obase + (t >> 4);
    float inv = g2[o] / sqrtf(v2[o] + BN_EPS);
    float4 w = ((const float4*)w2)[o * 16 + (t & 15)];
    sw[t] = make_float4(w.x*inv, w.y*inv, w.z*inv, w.w*inv);
  }
  __syncthreads();
  int gp = ng * 256 + threadIdx.x;
  float4 r[16];
  const float4* row = (const float4*)(h1 + (size_t)gp * C1);
#pragma unroll
  for (int i = 0; i < 16; ++i) r[i] = row[i];
  float* out = h2 + (size_t)gp * C2 + obase;
#pragma unroll 1
  for (int o = 0; o < 16; o += 4) {
    float4 res;
    float* rp = &res.x;
#pragma unroll
    for (int oo = 0; oo < 4; ++oo) {
      const float4* wrow = &sw[(o+oo) * 16];
      float acc = 0.f;
#pragma unroll
      for (int i = 0; i < 16; ++i) {
        float4 w = wrow[i];
        acc = fmaf(r[i].x, w.x, acc);
        acc = fmaf(r[i].y, w.y, acc);
        acc = fmaf(r[i].z, w.z, acc);
        acc = fmaf(r[i].w, w.w, acc);
      }
      rp[oo] = fmaxf(acc + sb[o+oo], 0.f);
    }
    *(float4*)(out + o) = res;
  }
}

// ---------------- K4: conv 128->256 + BN + ReLU fused with global max (out-split x8) ----------------
__global__ __launch_bounds__(256) void k4_conv3max(const float* __restrict__ h2,
    const float* __restrict__ w3, const float* __restrict__ g3, const float* __restrict__ b3,
    const float* __restrict__ m3, const float* __restrict__ v3, float* __restrict__ feat) {
  __shared__ float4 sw[32 * 32];            // 16 KiB: 32 outs x 128 in
  __shared__ float sb[32], sinv[32];
  __shared__ float lw[4 * 32];
  int bid = blockIdx.x;                     // 512 = b4 x nt16 x oq8
  int oq = bid & 7, nt = (bid >> 3) & 15, b = bid >> 7;
  int obase = oq * 32;
  if (threadIdx.x < 32) {
    int o = obase + threadIdx.x;
    float inv = g3[o] / sqrtf(v3[o] + BN_EPS);
    sinv[threadIdx.x] = inv;
    sb[threadIdx.x] = b3[o] - m3[o] * inv;
  }
  __syncthreads();
  for (int t = threadIdx.x; t < 32 * 32; t += 256) {
    float4 w = ((const float4*)w3)[(obase + (t >> 5)) * 32 + (t & 31)];
    float inv = sinv[t >> 5];
    sw[t] = make_float4(w.x*inv, w.y*inv, w.z*inv, w.w*inv);
  }
  __syncthreads();
  int n = nt * 256 + threadIdx.x;
  float4 r[32];
  const float4* row = (const float4*)(h2 + (size_t)(b * NPT + n) * C2);
#pragma unroll
  for (int i = 0; i < 32; ++i) r[i] = row[i];
  int lane = threadIdx.x & 63, wid = threadIdx.x >> 6;
#pragma unroll 1
  for (int ol = 0; ol < 32; ++ol) {
    const float4* wrow = &sw[ol * 32];
    float acc = 0.f;
#pragma unroll
    for (int i = 0; i < 32; ++i) {
      float4 w = wrow[i];
      acc = fmaf(r[i].x, w.x, acc);
      acc = fmaf(r[i].y, w.y, acc);
      acc = fmaf(r[i].z, w.z, acc);
      acc = fmaf(r[i].w, w.w, acc);
    }
    float v = fmaxf(acc + sb[ol], 0.f);
#pragma unroll
    for (int m = 32; m; m >>= 1) v = fmaxf(v, __shfl_xor(v, m));
    if (lane == 0) lw[wid * 32 + ol] = v;
  }
  __syncthreads();
  if (threadIdx.x < 32) {
    float m0 = fmaxf(fmaxf(lw[threadIdx.x], lw[32 + threadIdx.x]),
                     fmaxf(lw[64 + threadIdx.x], lw[96 + threadIdx.x]));
    atomicMax((int*)feat + b * C3 + obase + threadIdx.x, __float_as_int(m0));
  }
}

// ---------------- K6: FC head ----------------
__global__ __launch_bounds__(256) void k6_fc(const float* __restrict__ feat,
    const float* __restrict__ fc1w, const float* __restrict__ fc1b,
    const float* __restrict__ fc2w, const float* __restrict__ fc2b, float* __restrict__ out) {
  __shared__ float sf[NB * C3];
  __shared__ float sh[NB * 128];
  for (int t = threadIdx.x; t < NB * C3; t += 256) sf[t] = feat[t];
  __syncthreads();
  for (int t = threadIdx.x; t < NB * 128; t += 256) {
    int b = t >> 7, o = t & 127;
    float acc = fc1b[o];
    const float* w = fc1w + o * C3;
    const float* f = sf + b * C3;
    for (int c = 0; c < C3; ++c) acc = fmaf(f[c], w[c], acc);
    sh[t] = fmaxf(acc, 0.f);
  }
  __syncthreads();
  for (int t = threadIdx.x; t < NB * 40; t += 256) {
    int b = t / 40, o = t % 40;
    float acc = fc2b[o];
    const float* w = fc2w + o * 128;
    const float* hh = sh + b * 128;
    for (int c = 0; c < 128; ++c) acc = fmaf(hh[c], w[c], acc);
    out[b * 40 + o] = acc;
  }
}

extern "C" void kernel_launch(void* const* d_in, const int* in_sizes, int n_in,
                              void* d_out, int out_size, void* d_ws, size_t ws_size,
                              hipStream_t stream) {
  (void)in_sizes; (void)n_in; (void)out_size; (void)ws_size;
  const float* x   = (const float*)d_in[0];
  const float* w1  = (const float*)d_in[1];
  const float* g1  = (const float*)d_in[2];
  const float* b1  = (const float*)d_in[3];
  const float* m1  = (const float*)d_in[4];
  const float* v1  = (const float*)d_in[5];
  const float* w2  = (const float*)d_in[6];
  const float* g2  = (const float*)d_in[7];
  const float* b2  = (const float*)d_in[8];
  const float* m2  = (const float*)d_in[9];
  const float* v2  = (const float*)d_in[10];
  const float* w3  = (const float*)d_in[11];
  const float* g3  = (const float*)d_in[12];
  const float* b3  = (const float*)d_in[13];
  const float* m3  = (const float*)d_in[14];
  const float* v3  = (const float*)d_in[15];
  const float* f1w = (const float*)d_in[16];
  const float* f1b = (const float*)d_in[17];
  const float* f2w = (const float*)d_in[18];
  const float* f2b = (const float*)d_in[19];

  char* ws = (char*)d_ws;
  float4* xp   = (float4*)ws;                  // [0, 256K)
  float*  feat = (float*)(ws + 0x40000);       // [256K, +4K)
  int*    nbr  = (int*)  (ws + 0x80000);       // [512K, +1.25M)
  float*  h1   = (float*)(ws + 0x200000);      // [2M, 6M)
  float*  h2   = (float*)(ws + 0x600000);      // [6M, 14M)

  hipMemsetAsync(feat, 0, NB * C3 * sizeof(float), stream);
  k0_pack    <<<64, 256, 0, stream>>>(x, xp);
  k1_knn     <<<1024, 1024, 0, stream>>>(xp, nbr);
  k2_edge    <<<512, 256, 0, stream>>>(xp, nbr, w1, g1, b1, m1, v1, h1);
  k3_conv2   <<<512, 256, 0, stream>>>(h1, w2, g2, b2, m2, v2, h2);
  k4_conv3max<<<512, 256, 0, stream>>>(h2, w3, g3, b3, m3, v3, feat);
  k6_fc      <<<1, 256, 0, stream>>>(feat, f1w, f1b, f2w, f2b, (float*)d_out);
}

// Round 7
// 140.752 us; speedup vs baseline: 2.6038x; 1.0951x over previous
//
#include <hip/hip_runtime.h>
#include <math.h>

#define NB 4
#define NPT 4096
#define KNN 20
#define C1 64
#define C2 128
#define C3 256
#define BN_EPS 1e-5f

// pd computed once per candidate (cached in VGPRs), so no cross-phase identity
// concerns remain; keep contraction pinned anyway for determinism.
__device__ __forceinline__ float pd_of(float4 q, float nxx, float4 c) {
#pragma clang fp contract(off)
  float dot = fmaf(q.z, c.z, fmaf(q.y, c.y, q.x * c.x));
  float inner = -2.0f * dot;
  return (nxx - inner) - c.w;
}

// ---------------- K1: fused pack + exact kNN + edge-conv(6->64)+BN+ReLU+maxK ----------------
// 512-thread blocks, 8 queries each (wave per query), full batch staged in LDS (64KB+2KB).
// Prepass: pd[s] -> VGPRs + lane-max; bitonic -> m = 20th-largest lane-max (<= T20, lossless gate).
// Scan: register-only gated event-inserts into distributed top-20 key list (lanes 0..19).
// Epilogue: 20 broadcast LDS reads; lane o computes h1 channel o (max over k commutes exactly).
__global__ __launch_bounds__(512, 4) void k1_knn_edge(const float* __restrict__ x,
    const float* __restrict__ w1, const float* __restrict__ g1, const float* __restrict__ b1,
    const float* __restrict__ m1, const float* __restrict__ v1, float* __restrict__ h1) {
  __shared__ float4 pts[NPT];               // 64 KB
  __shared__ float4 swa[C1], swe[C1];       // 2 KB folded edge weights
  int bb = blockIdx.x >> 9;                 // 512 blocks per batch (never straddles)
  const float* xbs = x + (size_t)bb * NPT * 3;
  for (int t = threadIdx.x; t < NPT; t += 512) {
    float a = xbs[3*t], b = xbs[3*t+1], c = xbs[3*t+2];
    pts[t] = make_float4(a, b, c, fmaf(c, c, fmaf(b, b, a*a)));   // == reference xx chain
  }
  if (threadIdx.x < C1) {
    int o = threadIdx.x;
    float inv = g1[o] / sqrtf(v1[o] + BN_EPS);
    float bbx = b1[o] - m1[o] * inv;
    const float* w = w1 + o * 6;
    swa[o] = make_float4(w[0]*inv, w[1]*inv, w[2]*inv, 0.f);
    swe[o] = make_float4((w[3]-w[0])*inv, (w[4]-w[1])*inv, (w[5]-w[2])*inv, bbx);
  }
  __syncthreads();

  int lane = threadIdx.x & 63;
  int wq = threadIdx.x >> 6;                // 0..7
  int q = blockIdx.x * 8 + wq;
  int n = q & (NPT - 1);
  float4 qv = pts[n];
  float nxx = -qv.w;

  // ---- single LDS pass: pd -> registers, 4-way ILP lane-max ----
  float pd[64];
  float lm0 = -INFINITY, lm1 = -INFINITY, lm2 = -INFINITY, lm3 = -INFINITY;
#pragma unroll
  for (int s = 0; s < 64; s += 4) {
    pd[s+0] = pd_of(qv, nxx, pts[(s+0)*64 + lane]); lm0 = fmaxf(lm0, pd[s+0]);
    pd[s+1] = pd_of(qv, nxx, pts[(s+1)*64 + lane]); lm1 = fmaxf(lm1, pd[s+1]);
    pd[s+2] = pd_of(qv, nxx, pts[(s+2)*64 + lane]); lm2 = fmaxf(lm2, pd[s+2]);
    pd[s+3] = pd_of(qv, nxx, pts[(s+3)*64 + lane]); lm3 = fmaxf(lm3, pd[s+3]);
  }
  float lmax = fmaxf(fmaxf(lm0, lm1), fmaxf(lm2, lm3));

  // wave bitonic sort (ascending); m = element 44 = 20th-largest lane-max
  float v = lmax;
#pragma unroll
  for (int k = 2; k <= 64; k <<= 1) {
#pragma unroll
    for (int j2 = k >> 1; j2 > 0; j2 >>= 1) {
      float o = __shfl_xor(v, j2);
      bool keepmin = (((lane & k) == 0) == ((lane & j2) == 0));
      float mn = fminf(v, o), mx = fmaxf(v, o);
      v = keepmin ? mn : mx;
    }
  }
  float m = __shfl(v, 64 - KNN);

  // ---- register-only scan: u64 keys (value desc, index asc = lax.top_k order) ----
  unsigned long long lst = 0ull;            // lane t holds t-th largest key
  unsigned long long k19 = 0ull;            // 20th-largest key (wave-uniform)
  int rl = 4095 - lane;
#pragma unroll
  for (int s = 0; s < 64; ++s) {
    float p = pd[s];
    int ib = __float_as_int(p);
    unsigned uk = (unsigned)(ib ^ ((ib >> 31) | 0x80000000));   // monotone f32->u32
    unsigned long long cand = ((unsigned long long)uk << 12) | (unsigned)(rl - s * 64);
    unsigned long long mm = __ballot(p >= m && cand > k19);
    while (mm) {
      int src = __ffsll(mm) - 1;
      mm &= mm - 1;
      unsigned long long cv = __shfl(cand, src);
      if (cv > k19) {                       // wave-uniform; skips stale survivors
        unsigned long long kup = __shfl_up(lst, 1);
        if (lane == 0) kup = ~0ull;
        lst = (lst > cv) ? lst : ((kup > cv) ? cv : kup);
        k19 = __shfl(lst, 19);
      }
    }
  }

  // ---- fused edge-conv: lane o computes h1[q][o]; neighbors broadcast from LDS ----
  float4 a = swa[lane], e = swe[lane];
  float base = fmaf(e.z, qv.z, fmaf(e.y, qv.y, e.x * qv.x)) + e.w;
  float mx = -INFINITY;
#pragma unroll
  for (int k = 0; k < KNN; ++k) {
    int idx = 4095 - (int)(__shfl(lst, k) & 0xFFF);             // wave-uniform
    float4 nb = pts[idx];                                       // broadcast read
    mx = fmaxf(mx, fmaf(a.z, nb.z, fmaf(a.y, nb.y, a.x * nb.x)));
  }
  h1[(size_t)q * C1 + lane] = fmaxf(mx + base, 0.f);            // 256B coalesced per query
}

// ---------------- K3: conv 64->128 + BN + ReLU (out-split x8) ----------------
__global__ __launch_bounds__(256) void k3_conv2(const float* __restrict__ h1,
    const float* __restrict__ w2, const float* __restrict__ g2, const float* __restrict__ b2,
    const float* __restrict__ m2, const float* __restrict__ v2, float* __restrict__ h2) {
  __shared__ float4 sw[16 * 16];            // 4 KiB: this block's 16 outs
  __shared__ float sb[16];
  int qd = blockIdx.x & 7, ng = blockIdx.x >> 3;   // 512 blocks
  int obase = qd * 16;
  if (threadIdx.x < 16) {
    int o = obase + threadIdx.x;
    float inv = g2[o] / sqrtf(v2[o] + BN_EPS);
    sb[threadIdx.x] = b2[o] - m2[o] * inv;
  }
  for (int t = threadIdx.x; t < 16 * 16; t += 256) {
    int o = obase + (t >> 4);
    float inv = g2[o] / sqrtf(v2[o] + BN_EPS);
    float4 w = ((const float4*)w2)[o * 16 + (t & 15)];
    sw[t] = make_float4(w.x*inv, w.y*inv, w.z*inv, w.w*inv);
  }
  __syncthreads();
  int gp = ng * 256 + threadIdx.x;
  float4 r[16];
  const float4* row = (const float4*)(h1 + (size_t)gp * C1);
#pragma unroll
  for (int i = 0; i < 16; ++i) r[i] = row[i];
  float* out = h2 + (size_t)gp * C2 + obase;
#pragma unroll 1
  for (int o = 0; o < 16; o += 4) {
    float4 res;
    float* rp = &res.x;
#pragma unroll
    for (int oo = 0; oo < 4; ++oo) {
      const float4* wrow = &sw[(o+oo) * 16];
      float acc = 0.f;
#pragma unroll
      for (int i = 0; i < 16; ++i) {
        float4 w = wrow[i];
        acc = fmaf(r[i].x, w.x, acc);
        acc = fmaf(r[i].y, w.y, acc);
        acc = fmaf(r[i].z, w.z, acc);
        acc = fmaf(r[i].w, w.w, acc);
      }
      rp[oo] = fmaxf(acc + sb[o+oo], 0.f);
    }
    *(float4*)(out + o) = res;
  }
}

// ---------------- K4: conv 128->256 + BN + ReLU fused with global max (out-split x8) ----------------
__global__ __launch_bounds__(256) void k4_conv3max(const float* __restrict__ h2,
    const float* __restrict__ w3, const float* __restrict__ g3, const float* __restrict__ b3,
    const float* __restrict__ m3, const float* __restrict__ v3, float* __restrict__ feat) {
  __shared__ float4 sw[32 * 32];            // 16 KiB: 32 outs x 128 in
  __shared__ float sb[32], sinv[32];
  __shared__ float lw[4 * 32];
  int bid = blockIdx.x;                     // 512 = b4 x nt16 x oq8
  int oq = bid & 7, nt = (bid >> 3) & 15, b = bid >> 7;
  int obase = oq * 32;
  if (threadIdx.x < 32) {
    int o = obase + threadIdx.x;
    float inv = g3[o] / sqrtf(v3[o] + BN_EPS);
    sinv[threadIdx.x] = inv;
    sb[threadIdx.x] = b3[o] - m3[o] * inv;
  }
  __syncthreads();
  for (int t = threadIdx.x; t < 32 * 32; t += 256) {
    float4 w = ((const float4*)w3)[(obase + (t >> 5)) * 32 + (t & 31)];
    float inv = sinv[t >> 5];
    sw[t] = make_float4(w.x*inv, w.y*inv, w.z*inv, w.w*inv);
  }
  __syncthreads();
  int n = nt * 256 + threadIdx.x;
  float4 r[32];
  const float4* row = (const float4*)(h2 + (size_t)(b * NPT + n) * C2);
#pragma unroll
  for (int i = 0; i < 32; ++i) r[i] = row[i];
  int lane = threadIdx.x & 63, wid = threadIdx.x >> 6;
#pragma unroll 1
  for (int ol = 0; ol < 32; ++ol) {
    const float4* wrow = &sw[ol * 32];
    float acc = 0.f;
#pragma unroll
    for (int i = 0; i < 32; ++i) {
      float4 w = wrow[i];
      acc = fmaf(r[i].x, w.x, acc);
      acc = fmaf(r[i].y, w.y, acc);
      acc = fmaf(r[i].z, w.z, acc);
      acc = fmaf(r[i].w, w.w, acc);
    }
    float v = fmaxf(acc + sb[ol], 0.f);
#pragma unroll
    for (int m = 32; m; m >>= 1) v = fmaxf(v, __shfl_xor(v, m));
    if (lane == 0) lw[wid * 32 + ol] = v;
  }
  __syncthreads();
  if (threadIdx.x < 32) {
    float m0 = fmaxf(fmaxf(lw[threadIdx.x], lw[32 + threadIdx.x]),
                     fmaxf(lw[64 + threadIdx.x], lw[96 + threadIdx.x]));
    atomicMax((int*)feat + b * C3 + obase + threadIdx.x, __float_as_int(m0));
  }
}

// ---------------- K6: FC head ----------------
__global__ __launch_bounds__(256) void k6_fc(const float* __restrict__ feat,
    const float* __restrict__ fc1w, const float* __restrict__ fc1b,
    const float* __restrict__ fc2w, const float* __restrict__ fc2b, float* __restrict__ out) {
  __shared__ float sf[NB * C3];
  __shared__ float sh[NB * 128];
  for (int t = threadIdx.x; t < NB * C3; t += 256) sf[t] = feat[t];
  __syncthreads();
  for (int t = threadIdx.x; t < NB * 128; t += 256) {
    int b = t >> 7, o = t & 127;
    float acc = fc1b[o];
    const float* w = fc1w + o * C3;
    const float* f = sf + b * C3;
    for (int c = 0; c < C3; ++c) acc = fmaf(f[c], w[c], acc);
    sh[t] = fmaxf(acc, 0.f);
  }
  __syncthreads();
  for (int t = threadIdx.x; t < NB * 40; t += 256) {
    int b = t / 40, o = t % 40;
    float acc = fc2b[o];
    const float* w = fc2w + o * 128;
    const float* hh = sh + b * 128;
    for (int c = 0; c < 128; ++c) acc = fmaf(hh[c], w[c], acc);
    out[b * 40 + o] = acc;
  }
}

extern "C" void kernel_launch(void* const* d_in, const int* in_sizes, int n_in,
                              void* d_out, int out_size, void* d_ws, size_t ws_size,
                              hipStream_t stream) {
  (void)in_sizes; (void)n_in; (void)out_size; (void)ws_size;
  const float* x   = (const float*)d_in[0];
  const float* w1  = (const float*)d_in[1];
  const float* g1  = (const float*)d_in[2];
  const float* b1  = (const float*)d_in[3];
  const float* m1  = (const float*)d_in[4];
  const float* v1  = (const float*)d_in[5];
  const float* w2  = (const float*)d_in[6];
  const float* g2  = (const float*)d_in[7];
  const float* b2  = (const float*)d_in[8];
  const float* m2  = (const float*)d_in[9];
  const float* v2  = (const float*)d_in[10];
  const float* w3  = (const float*)d_in[11];
  const float* g3  = (const float*)d_in[12];
  const float* b3  = (const float*)d_in[13];
  const float* m3  = (const float*)d_in[14];
  const float* v3  = (const float*)d_in[15];
  const float* f1w = (const float*)d_in[16];
  const float* f1b = (const float*)d_in[17];
  const float* f2w = (const float*)d_in[18];
  const float* f2b = (const float*)d_in[19];

  char* ws = (char*)d_ws;
  float* feat = (float*)(ws + 0x40000);        // [256K, +4K)
  float* h1   = (float*)(ws + 0x200000);       // [2M, 6M)
  float* h2   = (float*)(ws + 0x600000);       // [6M, 14M)

  hipMemsetAsync(feat, 0, NB * C3 * sizeof(float), stream);
  k1_knn_edge<<<2048, 512, 0, stream>>>(x, w1, g1, b1, m1, v1, h1);
  k3_conv2   <<<512, 256, 0, stream>>>(h1, w2, g2, b2, m2, v2, h2);
  k4_conv3max<<<512, 256, 0, stream>>>(h2, w3, g3, b3, m3, v3, feat);
  k6_fc      <<<1, 256, 0, stream>>>(feat, f1w, f1b, f2w, f2b, (float*)d_out);
}

// Round 8
// 137.106 us; speedup vs baseline: 2.6731x; 1.0266x over previous
//
#include <hip/hip_runtime.h>
#include <math.h>

#define NB 4
#define NPT 4096
#define KNN 20
#define C1 64
#define C2 128
#define C3 256
#define BN_EPS 1e-5f

// pd computed identically in both passes (same LDS data, same op chain): pin contraction.
__device__ __forceinline__ float pd_of(float4 q, float nxx, float4 c) {
#pragma clang fp contract(off)
  float dot = fmaf(q.z, c.z, fmaf(q.y, c.y, q.x * c.x));
  float inner = -2.0f * dot;
  return (nxx - inner) - c.w;
}

__device__ __forceinline__ unsigned long long rl_u64(unsigned long long v, int src) {
  unsigned lo = __builtin_amdgcn_readlane((unsigned)v, src);
  unsigned hi = __builtin_amdgcn_readlane((unsigned)(v >> 32), src);
  return ((unsigned long long)hi << 32) | lo;
}

// ---------------- K1: fused pack + exact kNN + edge-conv(6->64)+BN+ReLU+maxK ----------------
// 512-thr blocks (8 waves), each wave owns 4 queries: one candidate ds_read_b128 feeds
// 4 pd computations (DS cost /4). Seed m = 20th-largest lane-max (bitonic, <= T20: lossless
// gate). Scan: distributed top-20 u64 key lists (value desc, index asc = lax.top_k order);
// event broadcasts via v_readlane (VALU) instead of ds_bpermute. Edge epilogue fused.
__global__ __launch_bounds__(512, 4) void k1_knn_edge(const float* __restrict__ x,
    const float* __restrict__ w1, const float* __restrict__ g1, const float* __restrict__ b1,
    const float* __restrict__ m1, const float* __restrict__ v1, float* __restrict__ h1) {
  __shared__ float4 pts[NPT];               // 64 KB
  __shared__ float4 swa[C1], swe[C1];       // 2 KB folded edge weights
  int bb = blockIdx.x >> 7;                 // 128 blocks per batch (never straddles)
  const float* xbs = x + (size_t)bb * NPT * 3;
  for (int t = threadIdx.x; t < NPT; t += 512) {
    float a = xbs[3*t], b = xbs[3*t+1], c = xbs[3*t+2];
    pts[t] = make_float4(a, b, c, fmaf(c, c, fmaf(b, b, a*a)));   // == reference xx chain
  }
  if (threadIdx.x < C1) {
    int o = threadIdx.x;
    float inv = g1[o] / sqrtf(v1[o] + BN_EPS);
    float bbx = b1[o] - m1[o] * inv;
    const float* w = w1 + o * 6;
    swa[o] = make_float4(w[0]*inv, w[1]*inv, w[2]*inv, 0.f);
    swe[o] = make_float4((w[3]-w[0])*inv, (w[4]-w[1])*inv, (w[5]-w[2])*inv, bbx);
  }
  __syncthreads();

  int lane = threadIdx.x & 63;
  int wv = threadIdx.x >> 6;                // wave 0..7
  int q0 = blockIdx.x * 32 + wv * 4;        // first of this wave's 4 queries (global id)

  float4 qv[4]; float nxx[4];
#pragma unroll
  for (int i = 0; i < 4; ++i) { qv[i] = pts[(q0 + i) & (NPT - 1)]; nxx[i] = -qv[i].w; }

  // ---- pass 1: lane-max per query (one b128 read serves 4 queries) ----
  float lm[4] = {-INFINITY, -INFINITY, -INFINITY, -INFINITY};
#pragma unroll 4
  for (int s = 0; s < 64; ++s) {
    float4 c = pts[s * 64 + lane];
#pragma unroll
    for (int i = 0; i < 4; ++i) lm[i] = fmaxf(lm[i], pd_of(qv[i], nxx[i], c));
  }

  // ---- seeds: bitonic sort (ascending) of lane-maxes; m = elem 44 = 20th largest ----
  float m[4];
#pragma unroll
  for (int i = 0; i < 4; ++i) {
    float v = lm[i];
#pragma unroll
    for (int k = 2; k <= 64; k <<= 1) {
#pragma unroll
      for (int j2 = k >> 1; j2 > 0; j2 >>= 1) {
        float o = __shfl_xor(v, j2);
        bool keepmin = (((lane & k) == 0) == ((lane & j2) == 0));
        float mn = fminf(v, o), mx = fmaxf(v, o);
        v = keepmin ? mn : mx;
      }
    }
    m[i] = __shfl(v, 64 - KNN);              // m <= true T20 (20 lanes have max >= m)
  }

  // ---- pass 2: gated event-inserts into distributed top-20 key lists ----
  unsigned long long lst[4] = {0ull, 0ull, 0ull, 0ull};   // lane t: t-th largest key
  unsigned long long k19[4] = {0ull, 0ull, 0ull, 0ull};   // 20th largest (wave-uniform)
#pragma unroll 2
  for (int s = 0; s < 64; ++s) {
    float4 c = pts[s * 64 + lane];
    int rj = 4095 - (s * 64 + lane);
#pragma unroll
    for (int i = 0; i < 4; ++i) {
      float p = pd_of(qv[i], nxx[i], c);
      int ib = __float_as_int(p);
      unsigned uk = (unsigned)(ib ^ ((ib >> 31) | 0x80000000));  // monotone f32->u32, !=0
      unsigned long long cand = ((unsigned long long)uk << 12) | (unsigned)rj;
      unsigned long long mm = __ballot(p >= m[i] && cand > k19[i]);
      while (mm) {
        int src = __ffsll(mm) - 1;
        mm &= mm - 1;
        unsigned long long cv = rl_u64(cand, src);        // VALU broadcast
        if (cv > k19[i]) {                                // uniform; skips stale survivors
          unsigned long long kup = __shfl_up(lst[i], 1);  // the only DS op per event
          if (lane == 0) kup = ~0ull;
          lst[i] = (lst[i] > cv) ? lst[i] : ((kup > cv) ? cv : kup);
          k19[i] = rl_u64(lst[i], 19);
        }
      }
    }
  }

  // ---- fused edge-conv: lane o computes channel o; neighbors broadcast from LDS ----
  float4 a = swa[lane], e = swe[lane];
#pragma unroll
  for (int i = 0; i < 4; ++i) {
    float base = fmaf(e.z, qv[i].z, fmaf(e.y, qv[i].y, e.x * qv[i].x)) + e.w;
    float mx = -INFINITY;
#pragma unroll
    for (int k = 0; k < KNN; ++k) {
      int idx = 4095 - (int)(__builtin_amdgcn_readlane((unsigned)lst[i], k) & 0xFFFu);
      float4 nb = pts[idx];                               // wave-uniform broadcast read
      mx = fmaxf(mx, fmaf(a.z, nb.z, fmaf(a.y, nb.y, a.x * nb.x)));
    }
    h1[(size_t)(q0 + i) * C1 + lane] = fmaxf(mx + base, 0.f);  // 256B coalesced
  }
}

// ---------------- K3: conv 64->128 + BN + ReLU (out-split x8) ----------------
__global__ __launch_bounds__(256) void k3_conv2(const float* __restrict__ h1,
    const float* __restrict__ w2, const float* __restrict__ g2, const float* __restrict__ b2,
    const float* __restrict__ m2, const float* __restrict__ v2, float* __restrict__ h2) {
  __shared__ float4 sw[16 * 16];            // 4 KiB: this block's 16 outs
  __shared__ float sb[16];
  int qd = blockIdx.x & 7, ng = blockIdx.x >> 3;   // 512 blocks
  int obase = qd * 16;
  if (threadIdx.x < 16) {
    int o = obase + threadIdx.x;
    float inv = g2[o] / sqrtf(v2[o] + BN_EPS);
    sb[threadIdx.x] = b2[o] - m2[o] * inv;
  }
  for (int t = threadIdx.x; t < 16 * 16; t += 256) {
    int o = obase + (t >> 4);
    float inv = g2[o] / sqrtf(v2[o] + BN_EPS);
    float4 w = ((const float4*)w2)[o * 16 + (t & 15)];
    sw[t] = make_float4(w.x*inv, w.y*inv, w.z*inv, w.w*inv);
  }
  __syncthreads();
  int gp = ng * 256 + threadIdx.x;
  float4 r[16];
  const float4* row = (const float4*)(h1 + (size_t)gp * C1);
#pragma unroll
  for (int i = 0; i < 16; ++i) r[i] = row[i];
  float* out = h2 + (size_t)gp * C2 + obase;
#pragma unroll 1
  for (int o = 0; o < 16; o += 4) {
    float4 res;
    float* rp = &res.x;
#pragma unroll
    for (int oo = 0; oo < 4; ++oo) {
      const float4* wrow = &sw[(o+oo) * 16];
      float acc = 0.f;
#pragma unroll
      for (int i = 0; i < 16; ++i) {
        float4 w = wrow[i];
        acc = fmaf(r[i].x, w.x, acc);
        acc = fmaf(r[i].y, w.y, acc);
        acc = fmaf(r[i].z, w.z, acc);
        acc = fmaf(r[i].w, w.w, acc);
      }
      rp[oo] = fmaxf(acc + sb[o+oo], 0.f);
    }
    *(float4*)(out + o) = res;
  }
}

// ---------------- K4: conv 128->256 + BN + ReLU fused with global max (out-split x8) ----------------
__global__ __launch_bounds__(256) void k4_conv3max(const float* __restrict__ h2,
    const float* __restrict__ w3, const float* __restrict__ g3, const float* __restrict__ b3,
    const float* __restrict__ m3, const float* __restrict__ v3, float* __restrict__ feat) {
  __shared__ float4 sw[32 * 32];            // 16 KiB: 32 outs x 128 in
  __shared__ float sb[32], sinv[32];
  __shared__ float lw[4 * 32];
  int bid = blockIdx.x;                     // 512 = b4 x nt16 x oq8
  int oq = bid & 7, nt = (bid >> 3) & 15, b = bid >> 7;
  int obase = oq * 32;
  if (threadIdx.x < 32) {
    int o = obase + threadIdx.x;
    float inv = g3[o] / sqrtf(v3[o] + BN_EPS);
    sinv[threadIdx.x] = inv;
    sb[threadIdx.x] = b3[o] - m3[o] * inv;
  }
  __syncthreads();
  for (int t = threadIdx.x; t < 32 * 32; t += 256) {
    float4 w = ((const float4*)w3)[(obase + (t >> 5)) * 32 + (t & 31)];
    float inv = sinv[t >> 5];
    sw[t] = make_float4(w.x*inv, w.y*inv, w.z*inv, w.w*inv);
  }
  __syncthreads();
  int n = nt * 256 + threadIdx.x;
  float4 r[32];
  const float4* row = (const float4*)(h2 + (size_t)(b * NPT + n) * C2);
#pragma unroll
  for (int i = 0; i < 32; ++i) r[i] = row[i];
  int lane = threadIdx.x & 63, wid = threadIdx.x >> 6;
#pragma unroll 1
  for (int ol = 0; ol < 32; ++ol) {
    const float4* wrow = &sw[ol * 32];
    float acc = 0.f;
#pragma unroll
    for (int i = 0; i < 32; ++i) {
      float4 w = wrow[i];
      acc = fmaf(r[i].x, w.x, acc);
      acc = fmaf(r[i].y, w.y, acc);
      acc = fmaf(r[i].z, w.z, acc);
      acc = fmaf(r[i].w, w.w, acc);
    }
    float v = fmaxf(acc + sb[ol], 0.f);
#pragma unroll
    for (int m = 32; m; m >>= 1) v = fmaxf(v, __shfl_xor(v, m));
    if (lane == 0) lw[wid * 32 + ol] = v;
  }
  __syncthreads();
  if (threadIdx.x < 32) {
    float m0 = fmaxf(fmaxf(lw[threadIdx.x], lw[32 + threadIdx.x]),
                     fmaxf(lw[64 + threadIdx.x], lw[96 + threadIdx.x]));
    atomicMax((int*)feat + b * C3 + obase + threadIdx.x, __float_as_int(m0));
  }
}

// ---------------- K6: FC head ----------------
__global__ __launch_bounds__(256) void k6_fc(const float* __restrict__ feat,
    const float* __restrict__ fc1w, const float* __restrict__ fc1b,
    const float* __restrict__ fc2w, const float* __restrict__ fc2b, float* __restrict__ out) {
  __shared__ float sf[NB * C3];
  __shared__ float sh[NB * 128];
  for (int t = threadIdx.x; t < NB * C3; t += 256) sf[t] = feat[t];
  __syncthreads();
  for (int t = threadIdx.x; t < NB * 128; t += 256) {
    int b = t >> 7, o = t & 127;
    float acc = fc1b[o];
    const float* w = fc1w + o * C3;
    const float* f = sf + b * C3;
    for (int c = 0; c < C3; ++c) acc = fmaf(f[c], w[c], acc);
    sh[t] = fmaxf(acc, 0.f);
  }
  __syncthreads();
  for (int t = threadIdx.x; t < NB * 40; t += 256) {
    int b = t / 40, o = t % 40;
    float acc = fc2b[o];
    const float* w = fc2w + o * 128;
    const float* hh = sh + b * 128;
    for (int c = 0; c < 128; ++c) acc = fmaf(hh[c], w[c], acc);
    out[b * 40 + o] = acc;
  }
}

extern "C" void kernel_launch(void* const* d_in, const int* in_sizes, int n_in,
                              void* d_out, int out_size, void* d_ws, size_t ws_size,
                              hipStream_t stream) {
  (void)in_sizes; (void)n_in; (void)out_size; (void)ws_size;
  const float* x   = (const float*)d_in[0];
  const float* w1  = (const float*)d_in[1];
  const float* g1  = (const float*)d_in[2];
  const float* b1  = (const float*)d_in[3];
  const float* m1  = (const float*)d_in[4];
  const float* v1  = (const float*)d_in[5];
  const float* w2  = (const float*)d_in[6];
  const float* g2  = (const float*)d_in[7];
  const float* b2  = (const float*)d_in[8];
  const float* m2  = (const float*)d_in[9];
  const float* v2  = (const float*)d_in[10];
  const float* w3  = (const float*)d_in[11];
  const float* g3  = (const float*)d_in[12];
  const float* b3  = (const float*)d_in[13];
  const float* m3  = (const float*)d_in[14];
  const float* v3  = (const float*)d_in[15];
  const float* f1w = (const float*)d_in[16];
  const float* f1b = (const float*)d_in[17];
  const float* f2w = (const float*)d_in[18];
  const float* f2b = (const float*)d_in[19];

  char* ws = (char*)d_ws;
  float* feat = (float*)(ws + 0x40000);        // [256K, +4K)
  float* h1   = (float*)(ws + 0x200000);       // [2M, 6M)
  float* h2   = (float*)(ws + 0x600000);       // [6M, 14M)

  hipMemsetAsync(feat, 0, NB * C3 * sizeof(float), stream);
  k1_knn_edge<<<512, 512, 0, stream>>>(x, w1, g1, b1, m1, v1, h1);
  k3_conv2   <<<512, 256, 0, stream>>>(h1, w2, g2, b2, m2, v2, h2);
  k4_conv3max<<<512, 256, 0, stream>>>(h2, w3, g3, b3, m3, v3, feat);
  k6_fc      <<<1, 256, 0, stream>>>(feat, f1w, f1b, f2w, f2b, (float*)d_out);
}

// Round 9
// 108.774 us; speedup vs baseline: 3.3693x; 1.2605x over previous
//
#include <hip/hip_runtime.h>
#include <math.h>

#define NB 4
#define NPT 4096
#define KNN 20
#define C1 64
#define C2 128
#define C3 256
#define BN_EPS 1e-5f

// pd computed identically in both passes (same LDS data, same op chain): pin contraction.
__device__ __forceinline__ float pd_of(float4 q, float nxx, float4 c) {
#pragma clang fp contract(off)
  float dot = fmaf(q.z, c.z, fmaf(q.y, c.y, q.x * c.x));
  float inner = -2.0f * dot;
  return (nxx - inner) - c.w;
}

__device__ __forceinline__ unsigned long long rl_u64(unsigned long long v, int src) {
  unsigned lo = __builtin_amdgcn_readlane((unsigned)v, src);
  unsigned hi = __builtin_amdgcn_readlane((unsigned)(v >> 32), src);
  return ((unsigned long long)hi << 32) | lo;
}

// ---------------- K1: fused pack + exact kNN + edge-conv(6->64)+BN+ReLU+maxK ----------------
// 512-thr blocks (8 waves), wave owns 4 queries (one ds_read_b128 feeds 4 pd).
// Pass1: lane-max + bitonic -> m = 20th-largest lane-max (<= T20: >=20 distinct candidates
// have pd >= m -> lossless gate). Pass2: f32-gated ballot (7 instr/pair common path);
// key build (value-desc, index-asc = lax.top_k order) only inside rare insert events.
__global__ __launch_bounds__(512, 4) void k1_knn_edge(const float* __restrict__ x,
    const float* __restrict__ w1, const float* __restrict__ g1, const float* __restrict__ b1,
    const float* __restrict__ m1, const float* __restrict__ v1, float* __restrict__ h1) {
  __shared__ float4 pts[NPT];               // 64 KB
  __shared__ float4 swa[C1], swe[C1];       // 2 KB folded edge weights
  int bb = blockIdx.x >> 7;                 // 128 blocks per batch (never straddles)
  const float* xbs = x + (size_t)bb * NPT * 3;
  for (int t = threadIdx.x; t < NPT; t += 512) {
    float a = xbs[3*t], b = xbs[3*t+1], c = xbs[3*t+2];
    pts[t] = make_float4(a, b, c, fmaf(c, c, fmaf(b, b, a*a)));   // == reference xx chain
  }
  if (threadIdx.x < C1) {
    int o = threadIdx.x;
    float inv = g1[o] / sqrtf(v1[o] + BN_EPS);
    float bbx = b1[o] - m1[o] * inv;
    const float* w = w1 + o * 6;
    swa[o] = make_float4(w[0]*inv, w[1]*inv, w[2]*inv, 0.f);
    swe[o] = make_float4((w[3]-w[0])*inv, (w[4]-w[1])*inv, (w[5]-w[2])*inv, bbx);
  }
  __syncthreads();

  int lane = threadIdx.x & 63;
  int wv = threadIdx.x >> 6;                // wave 0..7
  int q0 = blockIdx.x * 32 + wv * 4;        // first of this wave's 4 queries (global id)

  float4 qv[4]; float nxx[4];
#pragma unroll
  for (int i = 0; i < 4; ++i) { qv[i] = pts[(q0 + i) & (NPT - 1)]; nxx[i] = -qv[i].w; }

  // ---- pass 1: lane-max per query (one b128 read serves 4 queries) ----
  float lm[4] = {-INFINITY, -INFINITY, -INFINITY, -INFINITY};
#pragma unroll 4
  for (int s = 0; s < 64; ++s) {
    float4 c = pts[s * 64 + lane];
#pragma unroll
    for (int i = 0; i < 4; ++i) lm[i] = fmaxf(lm[i], pd_of(qv[i], nxx[i], c));
  }

  // ---- seeds: bitonic sort (ascending) of lane-maxes; m = elem 44 = 20th largest ----
  float m[4];
#pragma unroll
  for (int i = 0; i < 4; ++i) {
    float v = lm[i];
#pragma unroll
    for (int k = 2; k <= 64; k <<= 1) {
#pragma unroll
      for (int j2 = k >> 1; j2 > 0; j2 >>= 1) {
        float o = __shfl_xor(v, j2);
        bool keepmin = (((lane & k) == 0) == ((lane & j2) == 0));
        float mn = fminf(v, o), mx = fmaxf(v, o);
        v = keepmin ? mn : mx;
      }
    }
    m[i] = __shfl(v, 64 - KNN);              // m <= true T20
  }

  // ---- pass 2: f32-gated event-inserts into distributed top-20 key lists ----
  unsigned long long lst[4] = {0ull, 0ull, 0ull, 0ull};   // lane t: t-th largest key
  unsigned long long k19[4] = {0ull, 0ull, 0ull, 0ull};   // 20th largest (wave-uniform)
  float thr[4] = {m[0], m[1], m[2], m[3]};                // f32 value gate (grows past m)
#pragma unroll 2
  for (int s = 0; s < 64; ++s) {
    float4 c = pts[s * 64 + lane];
#pragma unroll
    for (int i = 0; i < 4; ++i) {
      float p = pd_of(qv[i], nxx[i], c);
      unsigned long long mm = __ballot(p >= thr[i]);
      while (mm) {
        int src = __ffsll(mm) - 1;
        mm &= mm - 1;
        // rebuild the candidate key from the source lane (event-rate work)
        float pv = __int_as_float(__builtin_amdgcn_readlane(__float_as_int(p), src));
        int ib = __float_as_int(pv);
        unsigned uk = (unsigned)(ib ^ ((ib >> 31) | 0x80000000));  // monotone f32->u32
        unsigned long long cv = ((unsigned long long)uk << 12)
                              | (unsigned)(4095 - (s * 64 + src));
        if (cv > k19[i]) {                                // exact (value, index) order
          unsigned long long kup = __shfl_up(lst[i], 1);
          if (lane == 0) kup = ~0ull;
          lst[i] = (lst[i] > cv) ? lst[i] : ((kup > cv) ? cv : kup);
          k19[i] = rl_u64(lst[i], 19);
          if (k19[i]) {                                   // decode value part -> f32 gate
            unsigned uk19 = (unsigned)(k19[i] >> 12);
            int ib19 = (uk19 & 0x80000000u) ? (int)(uk19 ^ 0x80000000u) : (int)~uk19;
            thr[i] = __int_as_float(ib19);
          }
        }
      }
    }
  }

  // ---- fused edge-conv: lane o computes channel o; neighbors broadcast from LDS ----
  float4 a = swa[lane], e = swe[lane];
#pragma unroll
  for (int i = 0; i < 4; ++i) {
    float base = fmaf(e.z, qv[i].z, fmaf(e.y, qv[i].y, e.x * qv[i].x)) + e.w;
    float mx = -INFINITY;
#pragma unroll
    for (int k = 0; k < KNN; ++k) {
      int idx = 4095 - (int)(__builtin_amdgcn_readlane((unsigned)lst[i], k) & 0xFFFu);
      float4 nb = pts[idx];                               // wave-uniform broadcast read
      mx = fmaxf(mx, fmaf(a.z, nb.z, fmaf(a.y, nb.y, a.x * nb.x)));
    }
    h1[(size_t)(q0 + i) * C1 + lane] = fmaxf(mx + base, 0.f);  // 256B coalesced
  }
}

// ---------------- K3: conv 64->128 + BN + ReLU (out-split x8, XCD-local rows) ----------------
// oq in HIGH bits: the 8 blocks sharing a row-group have equal bid%8 -> same XCD L2.
__global__ __launch_bounds__(256) void k3_conv2(const float* __restrict__ h1,
    const float* __restrict__ w2, const float* __restrict__ g2, const float* __restrict__ b2,
    const float* __restrict__ m2, const float* __restrict__ v2, float* __restrict__ h2) {
  __shared__ float4 sw[16 * 16];            // 4 KiB: this block's 16 outs
  __shared__ float sb[16];
  int qd = blockIdx.x >> 6, ng = blockIdx.x & 63;   // 512 blocks
  int obase = qd * 16;
  if (threadIdx.x < 16) {
    int o = obase + threadIdx.x;
    float inv = g2[o] / sqrtf(v2[o] + BN_EPS);
    sb[threadIdx.x] = b2[o] - m2[o] * inv;
  }
  for (int t = threadIdx.x; t < 16 * 16; t += 256) {
    int o = obase + (t >> 4);
    float inv = g2[o] / sqrtf(v2[o] + BN_EPS);
    float4 w = ((const float4*)w2)[o * 16 + (t & 15)];
    sw[t] = make_float4(w.x*inv, w.y*inv, w.z*inv, w.w*inv);
  }
  __syncthreads();
  int gp = ng * 256 + threadIdx.x;
  float4 r[16];
  const float4* row = (const float4*)(h1 + (size_t)gp * C1);
#pragma unroll
  for (int i = 0; i < 16; ++i) r[i] = row[i];
  float* out = h2 + (size_t)gp * C2 + obase;
#pragma unroll 1
  for (int o = 0; o < 16; o += 4) {
    float4 res;
    float* rp = &res.x;
#pragma unroll
    for (int oo = 0; oo < 4; ++oo) {
      const float4* wrow = &sw[(o+oo) * 16];
      float acc = 0.f;
#pragma unroll
      for (int i = 0; i < 16; ++i) {
        float4 w = wrow[i];
        acc = fmaf(r[i].x, w.x, acc);
        acc = fmaf(r[i].y, w.y, acc);
        acc = fmaf(r[i].z, w.z, acc);
        acc = fmaf(r[i].w, w.w, acc);
      }
      rp[oo] = fmaxf(acc + sb[o+oo], 0.f);
    }
    *(float4*)(out + o) = res;
  }
}

// ---------------- K4: conv 128->256 + BN + ReLU + global max (out-split x8, XCD-local) ----------------
__global__ __launch_bounds__(256) void k4_conv3max(const float* __restrict__ h2,
    const float* __restrict__ w3, const float* __restrict__ g3, const float* __restrict__ b3,
    const float* __restrict__ m3, const float* __restrict__ v3, float* __restrict__ feat) {
  __shared__ float4 sw[32 * 32];            // 16 KiB: 32 outs x 128 in
  __shared__ float sb[32], sinv[32];
  __shared__ float lw[4 * 32];
  int bid = blockIdx.x;                     // 512 = oq8 (high) x b4 x nt16
  int oq = bid >> 6, b = (bid >> 4) & 3, nt = bid & 15;
  int obase = oq * 32;
  if (threadIdx.x < 32) {
    int o = obase + threadIdx.x;
    float inv = g3[o] / sqrtf(v3[o] + BN_EPS);
    sinv[threadIdx.x] = inv;
    sb[threadIdx.x] = b3[o] - m3[o] * inv;
  }
  __syncthreads();
  for (int t = threadIdx.x; t < 32 * 32; t += 256) {
    float4 w = ((const float4*)w3)[(obase + (t >> 5)) * 32 + (t & 31)];
    float inv = sinv[t >> 5];
    sw[t] = make_float4(w.x*inv, w.y*inv, w.z*inv, w.w*inv);
  }
  __syncthreads();
  int n = nt * 256 + threadIdx.x;
  float4 r[32];
  const float4* row = (const float4*)(h2 + (size_t)(b * NPT + n) * C2);
#pragma unroll
  for (int i = 0; i < 32; ++i) r[i] = row[i];
  int lane = threadIdx.x & 63, wid = threadIdx.x >> 6;
#pragma unroll 1
  for (int ol = 0; ol < 32; ++ol) {
    const float4* wrow = &sw[ol * 32];
    float acc = 0.f;
#pragma unroll
    for (int i = 0; i < 32; ++i) {
      float4 w = wrow[i];
      acc = fmaf(r[i].x, w.x, acc);
      acc = fmaf(r[i].y, w.y, acc);
      acc = fmaf(r[i].z, w.z, acc);
      acc = fmaf(r[i].w, w.w, acc);
    }
    float v = fmaxf(acc + sb[ol], 0.f);
#pragma unroll
    for (int m = 32; m; m >>= 1) v = fmaxf(v, __shfl_xor(v, m));
    if (lane == 0) lw[wid * 32 + ol] = v;
  }
  __syncthreads();
  if (threadIdx.x < 32) {
    float m0 = fmaxf(fmaxf(lw[threadIdx.x], lw[32 + threadIdx.x]),
                     fmaxf(lw[64 + threadIdx.x], lw[96 + threadIdx.x]));
    atomicMax((int*)feat + b * C3 + obase + threadIdx.x, __float_as_int(m0));
  }
}

// ---------------- K6: FC head, one block per batch, split-dot parallel ----------------
__global__ __launch_bounds__(256) void k6_fc(const float* __restrict__ feat,
    const float* __restrict__ fc1w, const float* __restrict__ fc1b,
    const float* __restrict__ fc2w, const float* __restrict__ fc2b, float* __restrict__ out) {
  __shared__ float sf[C3];
  __shared__ float part[128][2];
  __shared__ float sh[128];
  __shared__ float p2[40][4];
  int b = blockIdx.x;
  int t = threadIdx.x;
  if (t < C3) sf[t] = feat[b * C3 + t];
  __syncthreads();
  {                                           // fc1: 128 outs x 2 half-dots
    int o = t >> 1, half = t & 1;
    const float* w = fc1w + o * C3 + half * 128;
    const float* f = sf + half * 128;
    float acc = 0.f;
#pragma unroll
    for (int c = 0; c < 128; ++c) acc = fmaf(f[c], w[c], acc);
    part[o][half] = acc;
  }
  __syncthreads();
  if (t < 128) sh[t] = fmaxf(part[t][0] + part[t][1] + fc1b[t], 0.f);
  __syncthreads();
  if (t < 160) {                              // fc2: 40 outs x 4 quarter-dots
    int o = t >> 2, qtr = t & 3;
    const float* w = fc2w + o * 128 + qtr * 32;
    float acc = 0.f;
#pragma unroll
    for (int c = 0; c < 32; ++c) acc = fmaf(sh[qtr * 32 + c], w[c], acc);
    p2[o][qtr] = acc;
  }
  __syncthreads();
  if (t < 40) out[b * 40 + t] = p2[t][0] + p2[t][1] + p2[t][2] + p2[t][3] + fc2b[t];
}

extern "C" void kernel_launch(void* const* d_in, const int* in_sizes, int n_in,
                              void* d_out, int out_size, void* d_ws, size_t ws_size,
                              hipStream_t stream) {
  (void)in_sizes; (void)n_in; (void)out_size; (void)ws_size;
  const float* x   = (const float*)d_in[0];
  const float* w1  = (const float*)d_in[1];
  const float* g1  = (const float*)d_in[2];
  const float* b1  = (const float*)d_in[3];
  const float* m1  = (const float*)d_in[4];
  const float* v1  = (const float*)d_in[5];
  const float* w2  = (const float*)d_in[6];
  const float* g2  = (const float*)d_in[7];
  const float* b2  = (const float*)d_in[8];
  const float* m2  = (const float*)d_in[9];
  const float* v2  = (const float*)d_in[10];
  const float* w3  = (const float*)d_in[11];
  const float* g3  = (const float*)d_in[12];
  const float* b3  = (const float*)d_in[13];
  const float* m3  = (const float*)d_in[14];
  const float* v3  = (const float*)d_in[15];
  const float* f1w = (const float*)d_in[16];
  const float* f1b = (const float*)d_in[17];
  const float* f2w = (const float*)d_in[18];
  const float* f2b = (const float*)d_in[19];

  char* ws = (char*)d_ws;
  float* feat = (float*)(ws + 0x40000);        // [256K, +4K)
  float* h1   = (float*)(ws + 0x200000);       // [2M, 6M)
  float* h2   = (float*)(ws + 0x600000);       // [6M, 14M)

  hipMemsetAsync(feat, 0, NB * C3 * sizeof(float), stream);
  k1_knn_edge<<<512, 512, 0, stream>>>(x, w1, g1, b1, m1, v1, h1);
  k3_conv2   <<<512, 256, 0, stream>>>(h1, w2, g2, b2, m2, v2, h2);
  k4_conv3max<<<512, 256, 0, stream>>>(h2, w3, g3, b3, m3, v3, feat);
  k6_fc      <<<NB, 256, 0, stream>>>(feat, f1w, f1b, f2w, f2b, (float*)d_out);
}